// Round 1
// baseline (258.138 us; speedup 1.0000x reference)
//
#include <hip/hip_runtime.h>
#include <math.h>

#define IN_CAP_N   1152
#define IN_CAP_SZ  5
#define OUT_CAP_N  55
#define NBATCH     8192

// One block (5 waves x 64 lanes) per batch element.
// Waves 0..4 each compute u_hat[b,i] = dot(u[b,i,:], W).
// Wave 0 then runs the 2-iteration dynamic routing for this batch.
__global__ __launch_bounds__(320) void digitcaps_kernel(
    const float* __restrict__ u,      // (B, 5, 1152)
    const float* __restrict__ W,      // (1, 1152, 1)
    const float* __restrict__ bparam, // (55, 1)
    float* __restrict__ out)          // (B, 55, 1)
{
    __shared__ float sW[IN_CAP_N];
    __shared__ float s_uhat[IN_CAP_SZ];

    const int tid  = threadIdx.x;
    const int wave = tid >> 6;   // 0..4
    const int lane = tid & 63;
    const int b    = blockIdx.x;

    // Stage W in LDS: 288 float4 loads, threads 0..287
    if (tid < IN_CAP_N / 4) {
        ((float4*)sW)[tid] = ((const float4*)W)[tid];
    }
    __syncthreads();

    // ---- u_hat: each wave reduces one 1152-float row --------------------
    const float* urow = u + ((size_t)b * IN_CAP_SZ + wave) * IN_CAP_N;
    float acc = 0.f;
    #pragma unroll
    for (int p = 0; p < 4; ++p) {
        int f = p * 64 + lane;                   // float4 index, 0..255
        float4 uv = ((const float4*)urow)[f];
        float4 wv = ((const float4*)sW)[f];
        acc += uv.x * wv.x + uv.y * wv.y + uv.z * wv.z + uv.w * wv.w;
    }
    if (lane < 32) {                             // remaining 32 float4 (256..287)
        int f = 256 + lane;
        float4 uv = ((const float4*)urow)[f];
        float4 wv = ((const float4*)sW)[f];
        acc += uv.x * wv.x + uv.y * wv.y + uv.z * wv.z + uv.w * wv.w;
    }
    #pragma unroll
    for (int off = 32; off > 0; off >>= 1)
        acc += __shfl_down(acc, off, 64);
    if (lane == 0) s_uhat[wave] = acc;
    __syncthreads();

    // ---- routing: wave 0, lane j in [0,55) owns out-capsule j -----------
    if (wave == 0) {
        float h[IN_CAP_SZ];
        #pragma unroll
        for (int i = 0; i < IN_CAP_SZ; ++i) h[i] = s_uhat[i];

        const bool active = (lane < OUT_CAP_N);
        float binit = active ? bparam[lane] : 0.f;
        float bij[IN_CAP_SZ];
        #pragma unroll
        for (int i = 0; i < IN_CAP_SZ; ++i) bij[i] = binit;

        float v = 0.f;
        #pragma unroll
        for (int it = 0; it < 2; ++it) {
            float c[IN_CAP_SZ];
            #pragma unroll
            for (int i = 0; i < IN_CAP_SZ; ++i) {
                // softmax over out-capsule dim (j = lane), column i
                float x = active ? bij[i] : -INFINITY;
                float m = x;
                #pragma unroll
                for (int off = 32; off > 0; off >>= 1)
                    m = fmaxf(m, __shfl_xor(m, off, 64));
                float e = active ? __expf(bij[i] - m) : 0.f;
                float sum = e;
                #pragma unroll
                for (int off = 32; off > 0; off >>= 1)
                    sum += __shfl_xor(sum, off, 64);
                c[i] = e / sum;
            }
            float s = 0.f;
            #pragma unroll
            for (int i = 0; i < IN_CAP_SZ; ++i) s += c[i] * h[i];
            // squash with OUT_CAP_SZ == 1: v = |s| * s / (1 + s^2)
            v = fabsf(s) * s / (1.f + s * s);
            #pragma unroll
            for (int i = 0; i < IN_CAP_SZ; ++i) bij[i] += v * h[i];
        }
        if (active) out[(size_t)b * OUT_CAP_N + lane] = v;
    }
}

extern "C" void kernel_launch(void* const* d_in, const int* in_sizes, int n_in,
                              void* d_out, int out_size, void* d_ws, size_t ws_size,
                              hipStream_t stream) {
    const float* u  = (const float*)d_in[0];
    const float* W  = (const float*)d_in[1];
    const float* bp = (const float*)d_in[2];
    float* out = (float*)d_out;
    digitcaps_kernel<<<NBATCH, 320, 0, stream>>>(u, W, bp, out);
}